// Round 5
// baseline (700.761 us; speedup 1.0000x reference)
//
#include <hip/hip_runtime.h>
#include <math.h>

#define DIMC 192
#define C3 576
#define NHEADS 8
#define CDh 24
#define HWN 16384
#define WIDTH 128
#define NBATCH 8

typedef __attribute__((ext_vector_type(8))) short short8;
typedef __attribute__((ext_vector_type(4))) float f32x4;

__device__ __forceinline__ ushort f2bf(float f) {
    uint u = __float_as_uint(f);
    u += 0x7fff + ((u >> 16) & 1);
    return (ushort)(u >> 16);
}
__device__ __forceinline__ float bf2f(ushort h) {
    return __uint_as_float(((uint)h) << 16);
}

// ============ K0: split W_qkv -> bf16 hi/lo ============
__global__ void k0_prep(const float* __restrict__ W, ushort* __restrict__ Wh,
                        ushort* __restrict__ Wl, int n) {
    int i = blockIdx.x * 256 + threadIdx.x;
    if (i < n) {
        float w = W[i];
        ushort h = f2bf(w);
        Wh[i] = h;
        Wl[i] = f2bf(w - bf2f(h));
    }
}

// ============ K0x: transpose+split x_b -> xTh/xTl [16384 px][192 ch] bf16 ============
// grid (256 px-tiles of 64, 3 ch-tiles of 64), block 256.
__global__ __launch_bounds__(256) void k0x_tr(const float* __restrict__ x,
                                              ushort* __restrict__ xTh,
                                              ushort* __restrict__ xTl, int b) {
    __shared__ float tile[64 * 65];
    const float* xb = x + (size_t)b * DIMC * HWN;
    const int px0 = blockIdx.x * 64, ch0 = blockIdx.y * 64;
    const int tid = threadIdx.x;
#pragma unroll
    for (int it = 0; it < 16; it++) {
        int f = tid + it * 256;
        int row = f >> 6, col = f & 63;
        tile[row * 65 + col] = xb[(size_t)(ch0 + row) * HWN + px0 + col];
    }
    __syncthreads();
    uint* dh = (uint*)xTh;
    uint* dl = (uint*)xTl;
#pragma unroll
    for (int s = 0; s < 8; s++) {
        int f = tid + s * 256;
        int pxl = f >> 5, uidx = f & 31;
        float v0 = tile[(2 * uidx) * 65 + pxl];
        float v1 = tile[(2 * uidx + 1) * 65 + pxl];
        ushort h0 = f2bf(v0), h1 = f2bf(v1);
        ushort l0 = f2bf(v0 - bf2f(h0)), l1 = f2bf(v1 - bf2f(h1));
        size_t dst = (size_t)(px0 + pxl) * 96 + (ch0 >> 1) + uidx;
        dh[dst] = (uint)h0 | ((uint)h1 << 16);
        dl[dst] = (uint)l0 | ((uint)l1 << 16);
    }
}

// ============ K1m: conv1x1 via split-bf16 MFMA, no LDS, no barriers ============
// grid (256 n-tiles of 64, 3 m-tiles of 192), block 256 (4 waves; wave = 48r x 64c).
// Writes qkv fp32 [576][16384] (bias included).
__global__ __launch_bounds__(256, 3) void k1m(const ushort* __restrict__ xTh,
                                              const ushort* __restrict__ xTl,
                                              const ushort* __restrict__ Wh,
                                              const ushort* __restrict__ Wl,
                                              const float* __restrict__ bias,
                                              float* __restrict__ qkv) {
    const int n0 = blockIdx.x * 64;
    const int o0 = blockIdx.y * 192;
    const int tid = threadIdx.x;
    const int wid = tid >> 6, lane = tid & 63;
    const int lr = lane & 15, lk = lane >> 4;
    const int mb = o0 + wid * 48;
    f32x4 acc[3][4];
#pragma unroll
    for (int i = 0; i < 3; i++)
#pragma unroll
        for (int j = 0; j < 4; j++) acc[i][j] = (f32x4)0.f;

    for (int kc = 0; kc < DIMC; kc += 32) {
        short8 bh[4], bl[4];
#pragma unroll
        for (int j = 0; j < 4; j++) {
            size_t boff = (size_t)(n0 + j * 16 + lr) * DIMC + kc + lk * 8;
            bh[j] = *(const short8*)&xTh[boff];
            bl[j] = *(const short8*)&xTl[boff];
        }
#pragma unroll
        for (int i = 0; i < 3; i++) {
            size_t aoff = (size_t)(mb + i * 16 + lr) * DIMC + kc + lk * 8;
            const short8 ah = *(const short8*)&Wh[aoff];
            const short8 al = *(const short8*)&Wl[aoff];
#pragma unroll
            for (int j = 0; j < 4; j++) {
                acc[i][j] = __builtin_amdgcn_mfma_f32_16x16x32_bf16(ah, bh[j], acc[i][j], 0, 0, 0);
                acc[i][j] = __builtin_amdgcn_mfma_f32_16x16x32_bf16(ah, bl[j], acc[i][j], 0, 0, 0);
                acc[i][j] = __builtin_amdgcn_mfma_f32_16x16x32_bf16(al, bh[j], acc[i][j], 0, 0, 0);
            }
        }
    }
#pragma unroll
    for (int i = 0; i < 3; i++) {
        int rbase = mb + i * 16 + lk * 4;
#pragma unroll
        for (int r = 0; r < 4; r++) {
            int row = rbase + r;
            float bsv = bias[row];
#pragma unroll
            for (int j = 0; j < 4; j++) {
                qkv[(size_t)row * HWN + n0 + j * 16 + lr] = acc[i][j][r] + bsv;
            }
        }
    }
}

// ============ K2: depthwise 3x3 + Gram/sumsq partials (fp32, R3-proven) ============
// grid (32 stripes of 4 rows, 8 heads), block 1024 (16 waves).
__global__ __launch_bounds__(1024, 4) void k2_dw(const float* __restrict__ qkv,
                                                 const float* __restrict__ wdw,
                                                 const float* __restrict__ bdw,
                                                 float* __restrict__ vout,
                                                 float* __restrict__ part, int b) {
    __shared__ float stage[6336];       // [8][6][132]
    __shared__ float qks[48 * 520];     // [qk ch][512 px + pad], fp32
    const int stripe = blockIdx.x, h = blockIdx.y;
    const int tid = threadIdx.x;
    const int r0 = stripe * 4;

    const int col4 = (tid & 31) * 4;
    const int orow = (tid >> 5) & 3;
    const int cc = tid >> 7;  // 0..7

    for (int chunk = 0; chunk < 9; chunk++) {
        const int g = chunk / 3, cb = (chunk % 3) * 8;
        __syncthreads();
#pragma unroll
        for (int f = tid; f < 1536; f += 1024) {
            int fc = f / 192, rem = f - fc * 192;
            int rl = rem >> 5, c4 = rem & 31;
            int gr = r0 - 1 + rl;
            int ch = g * DIMC + h * CDh + cb + fc;
            float4 v = make_float4(0.f, 0.f, 0.f, 0.f);
            if (gr >= 0 && gr < 128)
                v = *(const float4*)&qkv[(size_t)ch * HWN + gr * WIDTH + c4 * 4];
            *(float4*)&stage[(fc * 6 + rl) * 132 + c4 * 4] = v;
        }
        __syncthreads();
        {
            const int ch = g * DIMC + h * CDh + cb + cc;
            float wr[9];
#pragma unroll
            for (int t = 0; t < 9; t++) wr[t] = wdw[ch * 9 + t];
            float bsv = bdw[ch];
            float a0 = bsv, a1 = bsv, a2 = bsv, a3 = bsv;
#pragma unroll
            for (int dr = 0; dr < 3; dr++) {
                const float* row = &stage[(cc * 6 + orow + dr) * 132];
                float left = (col4 > 0) ? row[col4 - 1] : 0.f;
                float4 c = *(const float4*)&row[col4];
                float right = (col4 < 124) ? row[col4 + 4] : 0.f;
                float wA = wr[dr * 3 + 0], wB = wr[dr * 3 + 1], wC = wr[dr * 3 + 2];
                a0 = fmaf(left, wA, fmaf(c.x, wB, fmaf(c.y, wC, a0)));
                a1 = fmaf(c.x, wA, fmaf(c.y, wB, fmaf(c.z, wC, a1)));
                a2 = fmaf(c.y, wA, fmaf(c.z, wB, fmaf(c.w, wC, a2)));
                a3 = fmaf(c.z, wA, fmaf(c.w, wB, fmaf(right, wC, a3)));
            }
            float4 o4 = {a0, a1, a2, a3};
            if (g == 2) {
                *(float4*)&vout[((size_t)b * DIMC + h * CDh + cb + cc) * HWN +
                                (size_t)(r0 + orow) * WIDTH + col4] = o4;
            } else {
                *(float4*)&qks[(g * CDh + cb + cc) * 520 + orow * 128 + col4] = o4;
            }
        }
    }
    __syncthreads();  // qks complete

    const int tc = tid & 3, td = (tid >> 2) & 3, tp = tid >> 4;
    float ga[6][6];
#pragma unroll
    for (int i = 0; i < 6; i++)
#pragma unroll
        for (int j = 0; j < 6; j++) ga[i][j] = 0.f;
#pragma unroll
    for (int s = 0; s < 2; s++) {
        int px = tp * 8 + s * 4;
        f32x4 qv[6], kv[6];
#pragma unroll
        for (int i = 0; i < 6; i++) qv[i] = *(const f32x4*)&qks[(tc * 6 + i) * 520 + px];
#pragma unroll
        for (int j = 0; j < 6; j++) kv[j] = *(const f32x4*)&qks[(24 + td * 6 + j) * 520 + px];
#pragma unroll
        for (int i = 0; i < 6; i++)
#pragma unroll
            for (int j = 0; j < 6; j++) {
                ga[i][j] = fmaf(qv[i][0], kv[j][0], ga[i][j]);
                ga[i][j] = fmaf(qv[i][1], kv[j][1], ga[i][j]);
                ga[i][j] = fmaf(qv[i][2], kv[j][2], ga[i][j]);
                ga[i][j] = fmaf(qv[i][3], kv[j][3], ga[i][j]);
            }
    }
#pragma unroll
    for (int i = 0; i < 6; i++)
#pragma unroll
        for (int j = 0; j < 6; j++) {
            float v = ga[i][j];
            v += __shfl_xor(v, 16, 64);
            v += __shfl_xor(v, 32, 64);
            ga[i][j] = v;
        }
    float nv = 0.f;
    int nch = 0, npg = 0;
    if (tid < 768) {
        npg = tid / 48;
        nch = tid - npg * 48;
#pragma unroll
        for (int s = 0; s < 8; s++) {
            f32x4 v = *(const f32x4*)&qks[nch * 520 + npg * 32 + s * 4];
            nv = fmaf(v[0], v[0], nv);
            nv = fmaf(v[1], v[1], nv);
            nv = fmaf(v[2], v[2], nv);
            nv = fmaf(v[3], v[3], nv);
        }
    }
    __syncthreads();
    float* gscr = qks;  // [16][624]
    const int wave = tid >> 6;
    if ((tid & 63) < 16) {
#pragma unroll
        for (int i = 0; i < 6; i++)
#pragma unroll
            for (int j = 0; j < 6; j++)
                gscr[wave * 624 + (tc * 6 + i) * 24 + (td * 6 + j)] = ga[i][j];
    }
    if (tid < 768) gscr[npg * 624 + 576 + nch] = nv;
    __syncthreads();
    if (tid < 624) {
        float s = 0.f;
#pragma unroll
        for (int w2 = 0; w2 < 16; w2++) s += gscr[w2 * 624 + tid];
        part[((size_t)(b * NHEADS + h) * 624 + tid) * 32 + stripe] = s;
    }
}

// ============ K3: reduce stripe partials (fixed order) ============
__global__ void k3_reduce(const float* __restrict__ part, float* __restrict__ G,
                          float* __restrict__ nq, float* __restrict__ nk) {
    int bh = blockIdx.x;
    int b = bh >> 3, h = bh & 7;
    int tid = threadIdx.x;
    int lane = tid & 63, wave = tid >> 6;
    int half = lane >> 5, sl = lane & 31;
    for (int tp = wave; tp < 312; tp += 4) {
        int ti = tp * 2 + half;
        float v = part[((size_t)bh * 624 + ti) * 32 + sl];
        v += __shfl_xor(v, 1, 64);
        v += __shfl_xor(v, 2, 64);
        v += __shfl_xor(v, 4, 64);
        v += __shfl_xor(v, 8, 64);
        v += __shfl_xor(v, 16, 64);
        if (sl == 0) {
            if (ti < 576) G[bh * 576 + ti] = v;
            else if (ti < 600) nq[b * DIMC + h * CDh + (ti - 576)] = v;
            else nk[b * DIMC + h * CDh + (ti - 600)] = v;
        }
    }
}

// ============ K4a: attn + 4 top-k sparse softmaxes -> A_eff ============
__global__ void k4a_attn(const float* __restrict__ G, const float* __restrict__ nq,
                         const float* __restrict__ nk, const float* __restrict__ temp,
                         const float* __restrict__ a1, const float* __restrict__ a2,
                         const float* __restrict__ a3, const float* __restrict__ a4,
                         float* __restrict__ Aeff) {
    int h = blockIdx.x, b = blockIdx.y;
    int bh = b * NHEADS + h;
    int r = threadIdx.x;
    if (r >= CDh) return;
    float t = temp[h];
    float aw[4] = {a1[0], a2[0], a3[0], a4[0]};
    const int kks[4] = {12, 16, 18, 19};
    float qn = fmaxf(sqrtf(nq[b * DIMC + h * CDh + r]), 1e-12f);
    float av[24];
    for (int d = 0; d < 24; d++) {
        float kn = fmaxf(sqrtf(nk[b * DIMC + h * CDh + d]), 1e-12f);
        av[d] = G[bh * 576 + r * 24 + d] / (qn * kn) * t;
    }
    int rank[24];
    float m = -1e30f;
    for (int d = 0; d < 24; d++) {
        int rk = 0;
        for (int e = 0; e < 24; e++)
            rk += (av[e] > av[d]) || (av[e] == av[d] && e < d);
        rank[d] = rk;
        m = fmaxf(m, av[d]);
    }
    float ex[24], outv[24];
    for (int d = 0; d < 24; d++) { ex[d] = expf(av[d] - m); outv[d] = 0.f; }
    for (int i = 0; i < 4; i++) {
        float Z = 0.f;
        for (int d = 0; d < 24; d++) if (rank[d] < kks[i]) Z += ex[d];
        float inv = aw[i] / Z;
        for (int d = 0; d < 24; d++) if (rank[d] < kks[i]) outv[d] += ex[d] * inv;
    }
    for (int d = 0; d < 24; d++) Aeff[(bh * 24 + r) * 24 + d] = outv[d];
}

// ============ K4b: M_b = W_proj @ blockdiag(A_eff) -> bf16 hi/lo ============
__global__ void k4b_mmat(const float* __restrict__ Wp, const float* __restrict__ Aeff,
                         ushort* __restrict__ Mh, ushort* __restrict__ Ml) {
    int b = blockIdx.x;
    int e0 = blockIdx.y * 6144;
    for (int e = e0 + threadIdx.x; e < e0 + 6144; e += 256) {
        int o = e / DIMC, j = e % DIMC;
        int h = j / CDh, d = j % CDh;
        const float* wrow = Wp + o * DIMC + h * CDh;
        const float* acol = Aeff + (size_t)((b * NHEADS + h) * CDh) * CDh + d;
        float s = 0.f;
        for (int c = 0; c < CDh; c++) s = fmaf(wrow[c], acol[c * CDh], s);
        size_t idx = ((size_t)b * DIMC + o) * DIMC + j;
        ushort hb = f2bf(s);
        Mh[idx] = hb;
        Ml[idx] = f2bf(s - bf2f(hb));
    }
}

// ============ K5m: y = M_b @ v + b_proj, IN-PLACE on d_out (v -> y) ============
// grid (128 n-tiles of 128, 8 b), block 256 (4 waves; wave = 48 rows x 128 cols).
__global__ __launch_bounds__(256) void k5m(float* vy,
                                           const ushort* __restrict__ Mh,
                                           const ushort* __restrict__ Ml,
                                           const float* __restrict__ bias) {
    __shared__ float Bs[32 * 132];
    const int z = blockIdx.y;
    float* vb = vy + (size_t)z * DIMC * HWN;
    const ushort* Mhz = Mh + (size_t)z * DIMC * DIMC;
    const ushort* Mlz = Ml + (size_t)z * DIMC * DIMC;
    const int n0 = blockIdx.x * 128;
    const int tid = threadIdx.x;
    const int wid = tid >> 6, lane = tid & 63;
    const int lr = lane & 15, lk = lane >> 4;
    const int mb = wid * 48;
    f32x4 acc[3][8];
#pragma unroll
    for (int i = 0; i < 3; i++)
#pragma unroll
        for (int j = 0; j < 8; j++) acc[i][j] = (f32x4)0.f;

    for (int kc = 0; kc < DIMC; kc += 32) {
        __syncthreads();
#pragma unroll
        for (int it = 0; it < 4; it++) {
            int f4 = tid + it * 256;
            int r = f4 >> 5, c4 = (f4 & 31) * 4;
            *(f32x4*)&Bs[r * 132 + c4] =
                *(const f32x4*)&vb[(size_t)(kc + r) * HWN + n0 + c4];
        }
        __syncthreads();
        short8 bh[8], bl[8];
#pragma unroll
        for (int j = 0; j < 8; j++) {
            int n = j * 16 + lr;
            union { short8 s; uint u[4]; } H, L;
#pragma unroll
            for (int p = 0; p < 4; p++) {
                float v0 = Bs[(lk * 8 + 2 * p) * 132 + n];
                float v1 = Bs[(lk * 8 + 2 * p + 1) * 132 + n];
                ushort h0 = f2bf(v0), h1 = f2bf(v1);
                ushort l0 = f2bf(v0 - bf2f(h0)), l1 = f2bf(v1 - bf2f(h1));
                H.u[p] = (uint)h0 | ((uint)h1 << 16);
                L.u[p] = (uint)l0 | ((uint)l1 << 16);
            }
            bh[j] = H.s; bl[j] = L.s;
        }
#pragma unroll
        for (int i = 0; i < 3; i++) {
            size_t aoff = (size_t)(mb + i * 16 + lr) * DIMC + kc + lk * 8;
            const short8 ah = *(const short8*)&Mhz[aoff];
            const short8 al = *(const short8*)&Mlz[aoff];
#pragma unroll
            for (int j = 0; j < 8; j++) {
                acc[i][j] = __builtin_amdgcn_mfma_f32_16x16x32_bf16(ah, bh[j], acc[i][j], 0, 0, 0);
                acc[i][j] = __builtin_amdgcn_mfma_f32_16x16x32_bf16(ah, bl[j], acc[i][j], 0, 0, 0);
                acc[i][j] = __builtin_amdgcn_mfma_f32_16x16x32_bf16(al, bh[j], acc[i][j], 0, 0, 0);
            }
        }
    }
    __syncthreads();  // all B reads done before any in-place write
#pragma unroll
    for (int i = 0; i < 3; i++) {
        int rbase = mb + i * 16 + lk * 4;
#pragma unroll
        for (int r = 0; r < 4; r++) {
            int row = rbase + r;
            float bsv = bias[row];
#pragma unroll
            for (int j = 0; j < 8; j++) {
                vb[(size_t)row * HWN + n0 + j * 16 + lr] = acc[i][j][r] + bsv;
            }
        }
    }
}

extern "C" void kernel_launch(void* const* d_in, const int* in_sizes, int n_in,
                              void* d_out, int out_size, void* d_ws, size_t ws_size,
                              hipStream_t stream) {
    const float* x     = (const float*)d_in[0];
    const float* wqkv  = (const float*)d_in[1];
    const float* bqkv  = (const float*)d_in[2];
    const float* wdw   = (const float*)d_in[3];
    const float* bdw   = (const float*)d_in[4];
    const float* wproj = (const float*)d_in[5];
    const float* bproj = (const float*)d_in[6];
    const float* temp  = (const float*)d_in[7];
    const float* a1    = (const float*)d_in[8];
    const float* a2    = (const float*)d_in[9];
    const float* a3    = (const float*)d_in[10];
    const float* a4    = (const float*)d_in[11];
    float* out = (float*)d_out;

    float* ws = (float*)d_ws;
    // float-unit offsets (total ~57 MB)
    size_t o_part = 0;                               // 64*624*32 = 1,277,952
    size_t o_G    = o_part + (size_t)64 * 624 * 32;  // 36,864
    size_t o_nq   = o_G + (size_t)64 * 576;          // 1,536
    size_t o_nk   = o_nq + (size_t)NBATCH * DIMC;
    size_t o_A    = o_nk + (size_t)NBATCH * DIMC;    // 36,864
    size_t o_Mh   = o_A + (size_t)64 * 576;          // 147,456 (ushort half)
    size_t o_Ml   = o_Mh + (size_t)NBATCH * DIMC * DIMC / 2;
    size_t o_Wh   = o_Ml + (size_t)NBATCH * DIMC * DIMC / 2;   // 27,648
    size_t o_Wl   = o_Wh + (size_t)C3 * DIMC / 2;
    size_t o_xTh  = o_Wl + (size_t)C3 * DIMC / 2;    // per-batch 1,572,864
    size_t o_xTl  = o_xTh + (size_t)DIMC * HWN / 2;
    size_t o_qkv  = o_xTl + (size_t)DIMC * HWN / 2;  // 9,437,184

    float* part = ws + o_part;
    float* G    = ws + o_G;
    float* nq   = ws + o_nq;
    float* nk   = ws + o_nk;
    float* Aeff = ws + o_A;
    ushort* Mh  = (ushort*)(ws + o_Mh);
    ushort* Ml  = (ushort*)(ws + o_Ml);
    ushort* Wh  = (ushort*)(ws + o_Wh);
    ushort* Wl  = (ushort*)(ws + o_Wl);
    ushort* xTh = (ushort*)(ws + o_xTh);
    ushort* xTl = (ushort*)(ws + o_xTl);
    float* qkv  = ws + o_qkv;

    k0_prep<<<(C3 * DIMC + 255) / 256, 256, 0, stream>>>(wqkv, Wh, Wl, C3 * DIMC);

    for (int b = 0; b < NBATCH; b++) {
        k0x_tr<<<dim3(256, 3), 256, 0, stream>>>(x, xTh, xTl, b);
        k1m<<<dim3(256, 3), 256, 0, stream>>>(xTh, xTl, Wh, Wl, bqkv, qkv);
        k2_dw<<<dim3(32, 8), 1024, 0, stream>>>(qkv, wdw, bdw, out, part, b);
    }
    k3_reduce<<<64, 256, 0, stream>>>(part, G, nq, nk);
    k4a_attn<<<dim3(8, 8), 64, 0, stream>>>(G, nq, nk, temp, a1, a2, a3, a4, Aeff);
    k4b_mmat<<<dim3(8, 6), 256, 0, stream>>>(wproj, Aeff, Mh, Ml);
    k5m<<<dim3(128, 8), 256, 0, stream>>>(out, Mh, Ml, bproj);
}